// Round 1
// baseline (692.686 us; speedup 1.0000x reference)
//
#include <hip/hip_runtime.h>

// BondAwareEGNN fused layer — round 6.
//
// Round-5 post-mortem: msg_kernel 263us with MfmaUtil 9.7 / VALU 23.6 / HBM
// 13.7% — latency-bound at 43% occupancy (LDS 38400B -> 4 blocks/CU).
// node_kernel walks adjacency 4x with 1 load in flight.
//
// Round-6 changes:
//   1. msg: MsgB aliased onto Tbuf (wave-private rows, epilogue write is
//      data-dependent on all Tbuf reads -> safe). TPAD padding replaced by
//      XOR chunk swizzle (chunk ^= row&7): row stride 256B, bank rotation
//      from the XOR. LDS 38400 -> 19968 B => 8 blocks/CU (100% occupancy),
//      __launch_bounds__(256,8) (VGPR was 52, cap 64 is safe).
//   2. node: single-pass gather of the full 64B lane slice (32 fp32 acc),
//      2-way j unroll => 8 independent 16B loads in flight, adj read once
//      (was 4 passes x deg serial chained loads).
//   3. x_kernel fused into node_kernel: quad-0 lanes accumulate signed updv
//      in the same adjacency walk and write x_out. One dispatch removed.

#define H      128
#define NA     20000
#define NB     60000
#define NBATCH 8

typedef __bf16 bf16;
typedef __bf16 bf16x4 __attribute__((ext_vector_type(4)));
typedef __bf16 bf16x8 __attribute__((ext_vector_type(8)));
typedef float  f32x4  __attribute__((ext_vector_type(4)));

__device__ __forceinline__ float silu_f(float v) {
  float e = __expf(-v);
  return v * __builtin_amdgcn_rcpf(1.0f + e);  // 1-ulp rcp; inf -> 0 ok
}

// XOR-swizzled index into a [64][128] bf16 tile. Row stride 256B (bank
// neutral); 16B chunk index XOR'd with row&7 rotates banks. Bijective per
// row; 8-element chunks stay contiguous so bf16x8 loads/stores still work.
__device__ __forceinline__ int tswz(int row, int col) {
  return (row << 7) + (((((col) >> 3) ^ (row & 7)) << 3) | (col & 7));
}

__global__ void cast_h(const float* __restrict__ src, bf16* __restrict__ dst) {
  int i = blockIdx.x * 256 + threadIdx.x;  // one float4 per thread
  float4 v = *(const float4*)(src + (size_t)i * 4);
  bf16x4 t = {(bf16)v.x, (bf16)v.y, (bf16)v.z, (bf16)v.w};
  *(bf16x4*)(dst + (size_t)i * 4) = t;
}

// fp32 KxN(128) row-major -> bf16 fragment-linear (8 bf16 per lane-frag).
__global__ void pack_w(const float* __restrict__ src, bf16* __restrict__ dst,
                       int K) {
  int i = blockIdx.x * 256 + threadIdx.x;
  if (i >= K * 128) return;
  int k = i >> 7, n = i & 127;
  int nt = n >> 4, ks = k >> 5;
  int lane = (((k >> 3) & 3) << 4) | (n & 15);
  int j = k & 7;
  int KS = K >> 5;
  dst[((((nt * KS + ks) * 64) + lane) << 3) + j] = (bf16)src[i];
}

// ---------------- CSR build ----------------
__global__ void count_deg(const int* __restrict__ bonds,
                          int* __restrict__ degI) {
  int e = blockIdx.x * 256 + threadIdx.x;
  if (e >= NB) return;
  atomicAdd(&degI[bonds[2 * e]], 1);
  atomicAdd(&degI[bonds[2 * e + 1]], 1);
}

// single block, 1024 threads, wave-shfl scan (4 barriers per 1024-chunk)
__global__ void scan_offsets(const int* __restrict__ deg,
                             int* __restrict__ offsets) {
  __shared__ int wsum[16];
  __shared__ int carry;
  const int tid = threadIdx.x;
  const int wave = tid >> 6, lane = tid & 63;
  if (tid == 0) carry = 0;
  __syncthreads();
  for (int base = 0; base < NA; base += 1024) {
    int i = base + tid;
    int v = (i < NA) ? deg[i] : 0;
    int s = v;  // inclusive scan within wave
#pragma unroll
    for (int o = 1; o < 64; o <<= 1) {
      int t = __shfl_up(s, o);
      if (lane >= o) s += t;
    }
    if (lane == 63) wsum[wave] = s;
    __syncthreads();
    if (wave == 0) {  // scan the 16 wave totals
      int w = (lane < 16) ? wsum[lane] : 0;
#pragma unroll
      for (int o = 1; o < 16; o <<= 1) {
        int t = __shfl_up(w, o);
        if (lane >= o) w += t;
      }
      if (lane < 16) wsum[lane] = w;  // inclusive
    }
    __syncthreads();
    int pre = carry + (wave > 0 ? wsum[wave - 1] : 0);
    if (i < NA) offsets[i] = pre + s - v;  // exclusive
    __syncthreads();
    if (tid == 0) carry += wsum[15];
    __syncthreads();
  }
}

__global__ void build_adj(const int* __restrict__ bonds,
                          const int* __restrict__ offsets,
                          int* __restrict__ cursor, int* __restrict__ adj) {
  int e = blockIdx.x * 256 + threadIdx.x;
  if (e >= NB) return;
  int s = bonds[2 * e], d = bonds[2 * e + 1];
  int p = atomicAdd(&cursor[s], 1);
  adj[offsets[s] + p] = (e << 1);        // src endpoint (coord sign -)
  p = atomicAdd(&cursor[d], 1);
  adj[offsets[d] + p] = (e << 1) | 1;    // dst endpoint (coord sign +)
}

// ---------------- message kernel ----------------
__global__ __launch_bounds__(256, 8) void msg_kernel(
    const bf16* __restrict__ hb, const float* __restrict__ x,
    const int* __restrict__ bonds,
    const bf16* __restrict__ W1p, const float* __restrict__ bm1,
    const bf16* __restrict__ W2p, const float* __restrict__ bm2,
    const float* __restrict__ w1c,   // Wm1 row 256 (dist row), fp32[128]
    const bf16* __restrict__ Wc1p, const float* __restrict__ bc1,
    const float* __restrict__ Wc2,
    bf16* __restrict__ msgOut, float* __restrict__ updv) {
  // Single [64][128] swizzled tile: holds T after layer-1, then messages
  // after layer-2 (safe alias: epilogue writes depend on all reads).
  __shared__ __align__(16) bf16 Tbuf[64 * 128];
  __shared__ float cds[64 * 3];
  __shared__ float dists[64];
  __shared__ float bm1s[128], bm2s[128], w1cs[128], bc1s[128], wc2s[128];

  const int tid = threadIdx.x, blk = blockIdx.x;

  if (tid < 64) {
    int Rg = blk * 64 + tid;
    int bond = Rg >> 3, batch = Rg & 7;
    int s = bonds[2 * bond], dn = bonds[2 * bond + 1];
    const float* xs = x + (size_t)(batch * NA + s) * 3;
    const float* xd = x + (size_t)(batch * NA + dn) * 3;
    float c0 = xd[0] - xs[0], c1 = xd[1] - xs[1], c2 = xd[2] - xs[2];
    cds[tid * 3 + 0] = c0; cds[tid * 3 + 1] = c1; cds[tid * 3 + 2] = c2;
    dists[tid] = sqrtf(c0 * c0 + c1 * c1 + c2 * c2);
  }
  if (tid < 128) {
    bm1s[tid] = bm1[tid]; bm2s[tid] = bm2[tid]; w1cs[tid] = w1c[tid];
    bc1s[tid] = bc1[tid]; wc2s[tid] = Wc2[tid];
  }
  __syncthreads();   // the ONLY barrier

  const int lane = tid & 63;
  const int quad = lane >> 4, l16 = lane & 15;
  const int rowBase = (tid >> 6) * 16;
  const bf16x8* W1v = (const bf16x8*)W1p;
  const bf16x8* W2v = (const bf16x8*)W2p;
  const bf16x8* Wc1v = (const bf16x8*)Wc1p;

  // per-lane A-row metadata (row = rowBase + l16)
  const int RgA = blk * 64 + rowBase + l16;
  const int bondA = RgA >> 3, batA = RgA & 7;
  const int sA = bonds[2 * bondA], dA = bonds[2 * bondA + 1];
  const bf16* hsrc = hb + (size_t)(batA * NA + sA) * H;
  const bf16* hdst = hb + (size_t)(batA * NA + dA) * H;

  f32x4 acc[8];
#pragma unroll
  for (int nt = 0; nt < 8; nt++) acc[nt] = (f32x4){0.f, 0.f, 0.f, 0.f};

  // ---- layer 1: K = 256, A-fragments straight from global ----
#pragma unroll
  for (int ks = 0; ks < 4; ks++) {
    bf16x8 a = *(const bf16x8*)(hsrc + ks * 32 + quad * 8);
#pragma unroll
    for (int nt = 0; nt < 8; nt++) {
      bf16x8 b = W1v[(nt * 8 + ks) * 64 + lane];
      acc[nt] = __builtin_amdgcn_mfma_f32_16x16x32_bf16(a, b, acc[nt], 0, 0, 0);
    }
  }
#pragma unroll
  for (int ks = 4; ks < 8; ks++) {
    bf16x8 a = *(const bf16x8*)(hdst + (ks - 4) * 32 + quad * 8);
#pragma unroll
    for (int nt = 0; nt < 8; nt++) {
      bf16x8 b = W1v[(nt * 8 + ks) * 64 + lane];
      acc[nt] = __builtin_amdgcn_mfma_f32_16x16x32_bf16(a, b, acc[nt], 0, 0, 0);
    }
  }
  // t1 epilogue -> Tbuf (each wave touches only its own 16 rows: no barrier)
#pragma unroll
  for (int nt = 0; nt < 8; nt++) {
    int col = nt * 16 + l16;
    float bb = bm1s[col], wc = w1cs[col];
#pragma unroll
    for (int reg = 0; reg < 4; reg++) {
      int row = rowBase + quad * 4 + reg;
      float v = acc[nt][reg] + bb + dists[row] * wc;
      Tbuf[tswz(row, col)] = (bf16)silu_f(v);
    }
  }

  // ---- layer 2: K = 128 -> messages (written back over Tbuf) ----
#pragma unroll
  for (int nt = 0; nt < 8; nt++) acc[nt] = (f32x4){0.f, 0.f, 0.f, 0.f};
#pragma unroll
  for (int ks = 0; ks < 4; ks++) {
    bf16x8 a = *(const bf16x8*)&Tbuf[tswz(rowBase + l16, ks * 32 + quad * 8)];
#pragma unroll
    for (int nt = 0; nt < 8; nt++) {
      bf16x8 b = W2v[(nt * 4 + ks) * 64 + lane];
      acc[nt] = __builtin_amdgcn_mfma_f32_16x16x32_bf16(a, b, acc[nt], 0, 0, 0);
    }
  }
#pragma unroll
  for (int nt = 0; nt < 8; nt++) {
    int col = nt * 16 + l16;
    float bb = bm2s[col];
#pragma unroll
    for (int reg = 0; reg < 4; reg++) {
      int row = rowBase + quad * 4 + reg;
      Tbuf[tswz(row, col)] = (bf16)silu_f(acc[nt][reg] + bb);
    }
  }

  // ---- coord head: silu(messages @ Wc1 + bc1) @ Wc2 ----
#pragma unroll
  for (int nt = 0; nt < 8; nt++) acc[nt] = (f32x4){0.f, 0.f, 0.f, 0.f};
#pragma unroll
  for (int ks = 0; ks < 4; ks++) {
    bf16x8 a = *(const bf16x8*)&Tbuf[tswz(rowBase + l16, ks * 32 + quad * 8)];
#pragma unroll
    for (int nt = 0; nt < 8; nt++) {
      bf16x8 b = Wc1v[(nt * 4 + ks) * 64 + lane];
      acc[nt] = __builtin_amdgcn_mfma_f32_16x16x32_bf16(a, b, acc[nt], 0, 0, 0);
    }
  }

  // copy this wave's 16 message rows to global (coalesced 16B chunks)
#pragma unroll
  for (int i = 0; i < 4; i++) {
    int idx = i * 64 + lane;
    int row = rowBase + (idx >> 4), cg = idx & 15;
    *(bf16x8*)&msgOut[(size_t)(blk * 64 + row) * H + cg * 8] =
        *(const bf16x8*)&Tbuf[tswz(row, cg * 8)];
  }

  float cwp[4] = {0.f, 0.f, 0.f, 0.f};
#pragma unroll
  for (int nt = 0; nt < 8; nt++) {
    int col = nt * 16 + l16;
    float bb = bc1s[col], w2 = wc2s[col];
#pragma unroll
    for (int reg = 0; reg < 4; reg++)
      cwp[reg] += silu_f(acc[nt][reg] + bb) * w2;
  }
#pragma unroll
  for (int reg = 0; reg < 4; reg++) {
    float s = cwp[reg];
    s += __shfl_xor(s, 1);
    s += __shfl_xor(s, 2);
    s += __shfl_xor(s, 4);
    s += __shfl_xor(s, 8);
    cwp[reg] = s;
  }
  if (l16 == 0) {
#pragma unroll
    for (int reg = 0; reg < 4; reg++) {
      int row = rowBase + quad * 4 + reg;
      size_t Rg = (size_t)blk * 64 + row;
      float inv = 1.0f / (dists[row] + 1e-8f);
      float cw = cwp[reg];
#pragma unroll
      for (int c = 0; c < 3; c++)
        updv[Rg * 3 + c] = cds[row * 3 + c] * inv * cw;
    }
  }
}

// ---------------- node kernel (fused aggregation + x finalize) ----------------
// Layer-1 K=256 = [h (bf16, register-direct) | agg (single-pass CSR gather,
// full 64B lane slice, 2-way unrolled -> 8 loads in flight)]. quad-0 lanes
// also accumulate the signed updv sum for x_out in the same walk.
__global__ __launch_bounds__(256, 4) void node_kernel(
    const float* __restrict__ h, const bf16* __restrict__ hb,
    const bf16* __restrict__ msg, const float* __restrict__ updv,
    const int* __restrict__ offsets, const int* __restrict__ degI,
    const int* __restrict__ adj,
    const bf16* __restrict__ Wn1p, const float* __restrict__ bn1,
    const bf16* __restrict__ Wn2p, const float* __restrict__ bn2,
    const float* __restrict__ x,
    float* __restrict__ hout, float* __restrict__ xout) {
  __shared__ __align__(16) bf16 Tbuf[64 * 128];

  const int tid = threadIdx.x, blk = blockIdx.x;
  const int lane = tid & 63;
  const int quad = lane >> 4, l16 = lane & 15;
  const int rowBase = (tid >> 6) * 16;

  const int Rg = blk * 64 + rowBase + l16;   // batch*NA + atom
  const int atomA = Rg % NA, batA = Rg / NA;
  const int deg = degI[atomA], off = offsets[atomA];
  const bf16* hrow = hb + (size_t)Rg * H;
  const bf16x8* W1v = (const bf16x8*)Wn1p;
  const bf16x8* W2v = (const bf16x8*)Wn2p;

  f32x4 acc[8];
#pragma unroll
  for (int nt = 0; nt < 8; nt++) acc[nt] = (f32x4){0.f, 0.f, 0.f, 0.f};

  // layer-1 first half: h (bf16) register-direct
#pragma unroll
  for (int ks = 0; ks < 4; ks++) {
    bf16x8 a = *(const bf16x8*)(hrow + ks * 32 + quad * 8);
#pragma unroll
    for (int nt = 0; nt < 8; nt++) {
      bf16x8 b = W1v[(nt * 8 + ks) * 64 + lane];
      acc[nt] = __builtin_amdgcn_mfma_f32_16x16x32_bf16(a, b, acc[nt], 0, 0, 0);
    }
  }

  // layer-1 second half: aggregated — single-pass gather, fp32 acc in regs.
  // quad-0 lanes also accumulate the signed updv sum for x_out.
  float a32[32];
#pragma unroll
  for (int t = 0; t < 32; t++) a32[t] = 0.f;
  float sx = 0.f, sy = 0.f, sz = 0.f;
  {
    int j = 0;
    for (; j + 2 <= deg; j += 2) {
      int ent0 = adj[off + j], ent1 = adj[off + j + 1];
      const bf16* m0 = msg + ((size_t)(ent0 >> 1) * 8 + batA) * H + quad * 8;
      const bf16* m1 = msg + ((size_t)(ent1 >> 1) * 8 + batA) * H + quad * 8;
      bf16x8 v0 = *(const bf16x8*)(m0);
      bf16x8 v1 = *(const bf16x8*)(m0 + 32);
      bf16x8 v2 = *(const bf16x8*)(m0 + 64);
      bf16x8 v3 = *(const bf16x8*)(m0 + 96);
      bf16x8 u0 = *(const bf16x8*)(m1);
      bf16x8 u1 = *(const bf16x8*)(m1 + 32);
      bf16x8 u2 = *(const bf16x8*)(m1 + 64);
      bf16x8 u3 = *(const bf16x8*)(m1 + 96);
      if (quad == 0) {
        float sg0 = (ent0 & 1) ? 1.0f : -1.0f;
        float sg1 = (ent1 & 1) ? 1.0f : -1.0f;
        const float* uv0 = updv + ((size_t)(ent0 >> 1) * 8 + batA) * 3;
        const float* uv1 = updv + ((size_t)(ent1 >> 1) * 8 + batA) * 3;
        sx += sg0 * uv0[0] + sg1 * uv1[0];
        sy += sg0 * uv0[1] + sg1 * uv1[1];
        sz += sg0 * uv0[2] + sg1 * uv1[2];
      }
#pragma unroll
      for (int t = 0; t < 8; t++) {
        a32[t]      += (float)v0[t] + (float)u0[t];
        a32[8 + t]  += (float)v1[t] + (float)u1[t];
        a32[16 + t] += (float)v2[t] + (float)u2[t];
        a32[24 + t] += (float)v3[t] + (float)u3[t];
      }
    }
    if (j < deg) {
      int ent0 = adj[off + j];
      const bf16* m0 = msg + ((size_t)(ent0 >> 1) * 8 + batA) * H + quad * 8;
      if (quad == 0) {
        float sg0 = (ent0 & 1) ? 1.0f : -1.0f;
        const float* uv0 = updv + ((size_t)(ent0 >> 1) * 8 + batA) * 3;
        sx += sg0 * uv0[0]; sy += sg0 * uv0[1]; sz += sg0 * uv0[2];
      }
#pragma unroll
      for (int k = 0; k < 4; k++) {
        bf16x8 v = *(const bf16x8*)(m0 + 32 * k);
#pragma unroll
        for (int t = 0; t < 8; t++) a32[8 * k + t] += (float)v[t];
      }
    }
  }

  // x finalize (one lane per row)
  if (quad == 0) {
    float cnt = deg < 1 ? 1.0f : (float)deg;
    float inv = 1.0f / cnt;
    size_t o = (size_t)Rg * 3;
    xout[o + 0] = x[o + 0] + sx * inv;
    xout[o + 1] = x[o + 1] + sy * inv;
    xout[o + 2] = x[o + 2] + sz * inv;
  }

  // MFMA the aggregated half
#pragma unroll
  for (int ks2 = 0; ks2 < 4; ks2++) {
    bf16x8 af;
#pragma unroll
    for (int t = 0; t < 8; t++) af[t] = (bf16)a32[8 * ks2 + t];
#pragma unroll
    for (int nt = 0; nt < 8; nt++) {
      bf16x8 b = W1v[(nt * 8 + 4 + ks2) * 64 + lane];
      acc[nt] = __builtin_amdgcn_mfma_f32_16x16x32_bf16(af, b, acc[nt], 0, 0, 0);
    }
  }
#pragma unroll
  for (int nt = 0; nt < 8; nt++) {
    int col = nt * 16 + l16;
    float bb = bn1[col];
#pragma unroll
    for (int reg = 0; reg < 4; reg++) {
      int row = rowBase + quad * 4 + reg;
      Tbuf[tswz(row, col)] = (bf16)silu_f(acc[nt][reg] + bb);
    }
  }

#pragma unroll
  for (int nt = 0; nt < 8; nt++) acc[nt] = (f32x4){0.f, 0.f, 0.f, 0.f};
#pragma unroll
  for (int ks = 0; ks < 4; ks++) {
    bf16x8 a = *(const bf16x8*)&Tbuf[tswz(rowBase + l16, ks * 32 + quad * 8)];
#pragma unroll
    for (int nt = 0; nt < 8; nt++) {
      bf16x8 b = W2v[(nt * 4 + ks) * 64 + lane];
      acc[nt] = __builtin_amdgcn_mfma_f32_16x16x32_bf16(a, b, acc[nt], 0, 0, 0);
    }
  }
#pragma unroll
  for (int nt = 0; nt < 8; nt++) {
    int col = nt * 16 + l16;
    float bb = bn2[col];
#pragma unroll
    for (int reg = 0; reg < 4; reg++) {
      size_t Ro = (size_t)blk * 64 + rowBase + quad * 4 + reg;
      hout[Ro * H + col] = h[Ro * H + col] + acc[nt][reg] + bb;
    }
  }
}

extern "C" void kernel_launch(void* const* d_in, const int* in_sizes, int n_in,
                              void* d_out, int out_size, void* d_ws,
                              size_t ws_size, hipStream_t stream) {
  const float* h    = (const float*)d_in[0];
  const float* x    = (const float*)d_in[1];
  const int*  bonds = (const int*)d_in[2];
  const float* Wm1  = (const float*)d_in[3];
  const float* bm1  = (const float*)d_in[4];
  const float* Wm2  = (const float*)d_in[5];
  const float* bm2  = (const float*)d_in[6];
  const float* Wn1  = (const float*)d_in[7];
  const float* bn1  = (const float*)d_in[8];
  const float* Wn2  = (const float*)d_in[9];
  const float* bn2  = (const float*)d_in[10];
  const float* Wc1  = (const float*)d_in[11];
  const float* bc1  = (const float*)d_in[12];
  const float* Wc2  = (const float*)d_in[13];

  float* out  = (float*)d_out;
  float* hout = out;
  float* xout = out + (size_t)NBATCH * NA * H;

  char* ws = (char*)d_ws;
  // layout (bytes): NEED = 170,655,744 < 173,080,576 proven available.
  const size_t OFF_DEG  = 0;                        // NA int
  const size_t OFF_OFFS = 81920;                    // NA int
  const size_t OFF_CUR  = 163840;                   // NA int
  const size_t OFF_ADJ  = 245760;                   // 2*NB int = 480,000 B
  const size_t OFF_W1   = 786432;                   // 65,536 B
  const size_t OFF_W2   = OFF_W1 + 65536;           // 32,768
  const size_t OFF_WN1  = OFF_W2 + 32768;           // 65,536
  const size_t OFF_WN2  = OFF_WN1 + 65536;          // 32,768
  const size_t OFF_WC1  = OFF_WN2 + 32768;          // 32,768 (ends 1,015,808)
  const size_t OFF_UPDV = 1048576;                  // NB*8*3 f32 = 5,760,000
  const size_t OFF_HB   = 6815744;                  // 160000*128 bf16 = 40,960,000
  const size_t OFF_MSG  = 47775744;                 // NB*8*128 bf16 = 122,880,000

  int*   degI = (int*)(ws + OFF_DEG);
  int*   offs = (int*)(ws + OFF_OFFS);
  int*   cur  = (int*)(ws + OFF_CUR);
  int*   adj  = (int*)(ws + OFF_ADJ);
  bf16*  W1p  = (bf16*)(ws + OFF_W1);
  bf16*  W2p  = (bf16*)(ws + OFF_W2);
  bf16*  Wn1p = (bf16*)(ws + OFF_WN1);
  bf16*  Wn2p = (bf16*)(ws + OFF_WN2);
  bf16*  Wc1p = (bf16*)(ws + OFF_WC1);
  float* updv = (float*)(ws + OFF_UPDV);
  bf16*  hb   = (bf16*)(ws + OFF_HB);
  bf16*  msgB = (bf16*)(ws + OFF_MSG);

  (void)hipMemsetAsync(degI, 0, NA * sizeof(int), stream);
  (void)hipMemsetAsync(cur, 0, NA * sizeof(int), stream);

  cast_h<<<NBATCH * NA * H / 1024, 256, 0, stream>>>(h, hb);
  pack_w<<<128, 256, 0, stream>>>(Wm1, W1p, 256);
  pack_w<<<64, 256, 0, stream>>>(Wm2, W2p, 128);
  pack_w<<<128, 256, 0, stream>>>(Wn1, Wn1p, 256);
  pack_w<<<64, 256, 0, stream>>>(Wn2, Wn2p, 128);
  pack_w<<<64, 256, 0, stream>>>(Wc1, Wc1p, 128);

  count_deg<<<(NB + 255) / 256, 256, 0, stream>>>(bonds, degI);
  scan_offsets<<<1, 1024, 0, stream>>>(degI, offs);
  build_adj<<<(NB + 255) / 256, 256, 0, stream>>>(bonds, offs, cur, adj);

  msg_kernel<<<NB * NBATCH / 64, 256, 0, stream>>>(
      hb, x, bonds, W1p, bm1, W2p, bm2, Wm1 + 256 * H, Wc1p, bc1, Wc2,
      msgB, updv);
  node_kernel<<<NBATCH * NA / 64, 256, 0, stream>>>(
      h, hb, msgB, updv, offs, degI, adj, Wn1p, bn1, Wn2p, bn2, x,
      hout, xout);
}

// Round 2
// 635.585 us; speedup vs baseline: 1.0898x; 1.0898x over previous
//
#include <hip/hip_runtime.h>

// BondAwareEGNN fused layer — round 7.
//
// Round-6 post-mortem: __launch_bounds__(256,8) capped the unified
// VGPR/AGPR budget at 64 -> allocator spilled (VGPR_Count 52->32,
// hbm_bytes 2.9e8 -> 1.21e9, WRITE_SIZE 125MB -> 665MB of scratch
// traffic). Occupancy DID rise 43->83% — the LDS halving works.
//
// Round-7 change: keep the single swizzled Tbuf (19968B LDS => 8
// blocks/CU) but revert to __launch_bounds__(256,4) (VGPR cap 128).
// Round-5 evidence: this structure compiles to ~52 VGPR, under the
// 64-reg hardware step, so 8 waves/SIMD is granted without forcing
// the allocator. Node path unchanged (isolate one variable).

#define H      128
#define NA     20000
#define NB     60000
#define NBATCH 8

typedef __bf16 bf16;
typedef __bf16 bf16x4 __attribute__((ext_vector_type(4)));
typedef __bf16 bf16x8 __attribute__((ext_vector_type(8)));
typedef float  f32x4  __attribute__((ext_vector_type(4)));

__device__ __forceinline__ float silu_f(float v) {
  float e = __expf(-v);
  return v * __builtin_amdgcn_rcpf(1.0f + e);  // 1-ulp rcp; inf -> 0 ok
}

// XOR-swizzled index into a [64][128] bf16 tile. Row stride 256B (bank
// neutral); 16B chunk index XOR'd with row&7 rotates banks. Bijective per
// row; 8-element chunks stay contiguous so bf16x8 loads/stores still work.
__device__ __forceinline__ int tswz(int row, int col) {
  return (row << 7) + (((((col) >> 3) ^ (row & 7)) << 3) | (col & 7));
}

__global__ void cast_h(const float* __restrict__ src, bf16* __restrict__ dst) {
  int i = blockIdx.x * 256 + threadIdx.x;  // one float4 per thread
  float4 v = *(const float4*)(src + (size_t)i * 4);
  bf16x4 t = {(bf16)v.x, (bf16)v.y, (bf16)v.z, (bf16)v.w};
  *(bf16x4*)(dst + (size_t)i * 4) = t;
}

// fp32 KxN(128) row-major -> bf16 fragment-linear (8 bf16 per lane-frag).
__global__ void pack_w(const float* __restrict__ src, bf16* __restrict__ dst,
                       int K) {
  int i = blockIdx.x * 256 + threadIdx.x;
  if (i >= K * 128) return;
  int k = i >> 7, n = i & 127;
  int nt = n >> 4, ks = k >> 5;
  int lane = (((k >> 3) & 3) << 4) | (n & 15);
  int j = k & 7;
  int KS = K >> 5;
  dst[((((nt * KS + ks) * 64) + lane) << 3) + j] = (bf16)src[i];
}

// ---------------- CSR build ----------------
__global__ void count_deg(const int* __restrict__ bonds,
                          int* __restrict__ degI) {
  int e = blockIdx.x * 256 + threadIdx.x;
  if (e >= NB) return;
  atomicAdd(&degI[bonds[2 * e]], 1);
  atomicAdd(&degI[bonds[2 * e + 1]], 1);
}

// single block, 1024 threads, wave-shfl scan (4 barriers per 1024-chunk)
__global__ void scan_offsets(const int* __restrict__ deg,
                             int* __restrict__ offsets) {
  __shared__ int wsum[16];
  __shared__ int carry;
  const int tid = threadIdx.x;
  const int wave = tid >> 6, lane = tid & 63;
  if (tid == 0) carry = 0;
  __syncthreads();
  for (int base = 0; base < NA; base += 1024) {
    int i = base + tid;
    int v = (i < NA) ? deg[i] : 0;
    int s = v;  // inclusive scan within wave
#pragma unroll
    for (int o = 1; o < 64; o <<= 1) {
      int t = __shfl_up(s, o);
      if (lane >= o) s += t;
    }
    if (lane == 63) wsum[wave] = s;
    __syncthreads();
    if (wave == 0) {  // scan the 16 wave totals
      int w = (lane < 16) ? wsum[lane] : 0;
#pragma unroll
      for (int o = 1; o < 16; o <<= 1) {
        int t = __shfl_up(w, o);
        if (lane >= o) w += t;
      }
      if (lane < 16) wsum[lane] = w;  // inclusive
    }
    __syncthreads();
    int pre = carry + (wave > 0 ? wsum[wave - 1] : 0);
    if (i < NA) offsets[i] = pre + s - v;  // exclusive
    __syncthreads();
    if (tid == 0) carry += wsum[15];
    __syncthreads();
  }
}

__global__ void build_adj(const int* __restrict__ bonds,
                          const int* __restrict__ offsets,
                          int* __restrict__ cursor, int* __restrict__ adj) {
  int e = blockIdx.x * 256 + threadIdx.x;
  if (e >= NB) return;
  int s = bonds[2 * e], d = bonds[2 * e + 1];
  int p = atomicAdd(&cursor[s], 1);
  adj[offsets[s] + p] = (e << 1);        // src endpoint (coord sign -)
  p = atomicAdd(&cursor[d], 1);
  adj[offsets[d] + p] = (e << 1) | 1;    // dst endpoint (coord sign +)
}

// ---------------- message kernel ----------------
__global__ __launch_bounds__(256, 4) void msg_kernel(
    const bf16* __restrict__ hb, const float* __restrict__ x,
    const int* __restrict__ bonds,
    const bf16* __restrict__ W1p, const float* __restrict__ bm1,
    const bf16* __restrict__ W2p, const float* __restrict__ bm2,
    const float* __restrict__ w1c,   // Wm1 row 256 (dist row), fp32[128]
    const bf16* __restrict__ Wc1p, const float* __restrict__ bc1,
    const float* __restrict__ Wc2,
    bf16* __restrict__ msgOut, float* __restrict__ updv) {
  // Single [64][128] swizzled tile: holds T after layer-1, then messages
  // after layer-2 (safe alias: epilogue writes depend on all reads).
  __shared__ __align__(16) bf16 Tbuf[64 * 128];
  __shared__ float cds[64 * 3];
  __shared__ float dists[64];
  __shared__ float bm1s[128], bm2s[128], w1cs[128], bc1s[128], wc2s[128];

  const int tid = threadIdx.x, blk = blockIdx.x;

  if (tid < 64) {
    int Rg = blk * 64 + tid;
    int bond = Rg >> 3, batch = Rg & 7;
    int s = bonds[2 * bond], dn = bonds[2 * bond + 1];
    const float* xs = x + (size_t)(batch * NA + s) * 3;
    const float* xd = x + (size_t)(batch * NA + dn) * 3;
    float c0 = xd[0] - xs[0], c1 = xd[1] - xs[1], c2 = xd[2] - xs[2];
    cds[tid * 3 + 0] = c0; cds[tid * 3 + 1] = c1; cds[tid * 3 + 2] = c2;
    dists[tid] = sqrtf(c0 * c0 + c1 * c1 + c2 * c2);
  }
  if (tid < 128) {
    bm1s[tid] = bm1[tid]; bm2s[tid] = bm2[tid]; w1cs[tid] = w1c[tid];
    bc1s[tid] = bc1[tid]; wc2s[tid] = Wc2[tid];
  }
  __syncthreads();   // the ONLY barrier

  const int lane = tid & 63;
  const int quad = lane >> 4, l16 = lane & 15;
  const int rowBase = (tid >> 6) * 16;
  const bf16x8* W1v = (const bf16x8*)W1p;
  const bf16x8* W2v = (const bf16x8*)W2p;
  const bf16x8* Wc1v = (const bf16x8*)Wc1p;

  // per-lane A-row metadata (row = rowBase + l16)
  const int RgA = blk * 64 + rowBase + l16;
  const int bondA = RgA >> 3, batA = RgA & 7;
  const int sA = bonds[2 * bondA], dA = bonds[2 * bondA + 1];
  const bf16* hsrc = hb + (size_t)(batA * NA + sA) * H;
  const bf16* hdst = hb + (size_t)(batA * NA + dA) * H;

  f32x4 acc[8];
#pragma unroll
  for (int nt = 0; nt < 8; nt++) acc[nt] = (f32x4){0.f, 0.f, 0.f, 0.f};

  // ---- layer 1: K = 256, A-fragments straight from global ----
#pragma unroll
  for (int ks = 0; ks < 4; ks++) {
    bf16x8 a = *(const bf16x8*)(hsrc + ks * 32 + quad * 8);
#pragma unroll
    for (int nt = 0; nt < 8; nt++) {
      bf16x8 b = W1v[(nt * 8 + ks) * 64 + lane];
      acc[nt] = __builtin_amdgcn_mfma_f32_16x16x32_bf16(a, b, acc[nt], 0, 0, 0);
    }
  }
#pragma unroll
  for (int ks = 4; ks < 8; ks++) {
    bf16x8 a = *(const bf16x8*)(hdst + (ks - 4) * 32 + quad * 8);
#pragma unroll
    for (int nt = 0; nt < 8; nt++) {
      bf16x8 b = W1v[(nt * 8 + ks) * 64 + lane];
      acc[nt] = __builtin_amdgcn_mfma_f32_16x16x32_bf16(a, b, acc[nt], 0, 0, 0);
    }
  }
  // t1 epilogue -> Tbuf (each wave touches only its own 16 rows: no barrier)
#pragma unroll
  for (int nt = 0; nt < 8; nt++) {
    int col = nt * 16 + l16;
    float bb = bm1s[col], wc = w1cs[col];
#pragma unroll
    for (int reg = 0; reg < 4; reg++) {
      int row = rowBase + quad * 4 + reg;
      float v = acc[nt][reg] + bb + dists[row] * wc;
      Tbuf[tswz(row, col)] = (bf16)silu_f(v);
    }
  }

  // ---- layer 2: K = 128 -> messages (written back over Tbuf) ----
#pragma unroll
  for (int nt = 0; nt < 8; nt++) acc[nt] = (f32x4){0.f, 0.f, 0.f, 0.f};
#pragma unroll
  for (int ks = 0; ks < 4; ks++) {
    bf16x8 a = *(const bf16x8*)&Tbuf[tswz(rowBase + l16, ks * 32 + quad * 8)];
#pragma unroll
    for (int nt = 0; nt < 8; nt++) {
      bf16x8 b = W2v[(nt * 4 + ks) * 64 + lane];
      acc[nt] = __builtin_amdgcn_mfma_f32_16x16x32_bf16(a, b, acc[nt], 0, 0, 0);
    }
  }
#pragma unroll
  for (int nt = 0; nt < 8; nt++) {
    int col = nt * 16 + l16;
    float bb = bm2s[col];
#pragma unroll
    for (int reg = 0; reg < 4; reg++) {
      int row = rowBase + quad * 4 + reg;
      Tbuf[tswz(row, col)] = (bf16)silu_f(acc[nt][reg] + bb);
    }
  }

  // ---- coord head: silu(messages @ Wc1 + bc1) @ Wc2 ----
#pragma unroll
  for (int nt = 0; nt < 8; nt++) acc[nt] = (f32x4){0.f, 0.f, 0.f, 0.f};
#pragma unroll
  for (int ks = 0; ks < 4; ks++) {
    bf16x8 a = *(const bf16x8*)&Tbuf[tswz(rowBase + l16, ks * 32 + quad * 8)];
#pragma unroll
    for (int nt = 0; nt < 8; nt++) {
      bf16x8 b = Wc1v[(nt * 4 + ks) * 64 + lane];
      acc[nt] = __builtin_amdgcn_mfma_f32_16x16x32_bf16(a, b, acc[nt], 0, 0, 0);
    }
  }

  // copy this wave's 16 message rows to global (coalesced 16B chunks)
#pragma unroll
  for (int i = 0; i < 4; i++) {
    int idx = i * 64 + lane;
    int row = rowBase + (idx >> 4), cg = idx & 15;
    *(bf16x8*)&msgOut[(size_t)(blk * 64 + row) * H + cg * 8] =
        *(const bf16x8*)&Tbuf[tswz(row, cg * 8)];
  }

  float cwp[4] = {0.f, 0.f, 0.f, 0.f};
#pragma unroll
  for (int nt = 0; nt < 8; nt++) {
    int col = nt * 16 + l16;
    float bb = bc1s[col], w2 = wc2s[col];
#pragma unroll
    for (int reg = 0; reg < 4; reg++)
      cwp[reg] += silu_f(acc[nt][reg] + bb) * w2;
  }
#pragma unroll
  for (int reg = 0; reg < 4; reg++) {
    float s = cwp[reg];
    s += __shfl_xor(s, 1);
    s += __shfl_xor(s, 2);
    s += __shfl_xor(s, 4);
    s += __shfl_xor(s, 8);
    cwp[reg] = s;
  }
  if (l16 == 0) {
#pragma unroll
    for (int reg = 0; reg < 4; reg++) {
      int row = rowBase + quad * 4 + reg;
      size_t Rg = (size_t)blk * 64 + row;
      float inv = 1.0f / (dists[row] + 1e-8f);
      float cw = cwp[reg];
#pragma unroll
      for (int c = 0; c < 3; c++)
        updv[Rg * 3 + c] = cds[row * 3 + c] * inv * cw;
    }
  }
}

// ---------------- node kernel (fused aggregation + x finalize) ----------------
// Layer-1 K=256 = [h (bf16, register-direct) | agg (single-pass CSR gather,
// full 64B lane slice, 2-way unrolled -> 8 loads in flight)]. quad-0 lanes
// also accumulate the signed updv sum for x_out in the same walk.
__global__ __launch_bounds__(256, 4) void node_kernel(
    const float* __restrict__ h, const bf16* __restrict__ hb,
    const bf16* __restrict__ msg, const float* __restrict__ updv,
    const int* __restrict__ offsets, const int* __restrict__ degI,
    const int* __restrict__ adj,
    const bf16* __restrict__ Wn1p, const float* __restrict__ bn1,
    const bf16* __restrict__ Wn2p, const float* __restrict__ bn2,
    const float* __restrict__ x,
    float* __restrict__ hout, float* __restrict__ xout) {
  __shared__ __align__(16) bf16 Tbuf[64 * 128];

  const int tid = threadIdx.x, blk = blockIdx.x;
  const int lane = tid & 63;
  const int quad = lane >> 4, l16 = lane & 15;
  const int rowBase = (tid >> 6) * 16;

  const int Rg = blk * 64 + rowBase + l16;   // batch*NA + atom
  const int atomA = Rg % NA, batA = Rg / NA;
  const int deg = degI[atomA], off = offsets[atomA];
  const bf16* hrow = hb + (size_t)Rg * H;
  const bf16x8* W1v = (const bf16x8*)Wn1p;
  const bf16x8* W2v = (const bf16x8*)Wn2p;

  f32x4 acc[8];
#pragma unroll
  for (int nt = 0; nt < 8; nt++) acc[nt] = (f32x4){0.f, 0.f, 0.f, 0.f};

  // layer-1 first half: h (bf16) register-direct
#pragma unroll
  for (int ks = 0; ks < 4; ks++) {
    bf16x8 a = *(const bf16x8*)(hrow + ks * 32 + quad * 8);
#pragma unroll
    for (int nt = 0; nt < 8; nt++) {
      bf16x8 b = W1v[(nt * 8 + ks) * 64 + lane];
      acc[nt] = __builtin_amdgcn_mfma_f32_16x16x32_bf16(a, b, acc[nt], 0, 0, 0);
    }
  }

  // layer-1 second half: aggregated — single-pass gather, fp32 acc in regs.
  // quad-0 lanes also accumulate the signed updv sum for x_out.
  float a32[32];
#pragma unroll
  for (int t = 0; t < 32; t++) a32[t] = 0.f;
  float sx = 0.f, sy = 0.f, sz = 0.f;
  {
    int j = 0;
    for (; j + 2 <= deg; j += 2) {
      int ent0 = adj[off + j], ent1 = adj[off + j + 1];
      const bf16* m0 = msg + ((size_t)(ent0 >> 1) * 8 + batA) * H + quad * 8;
      const bf16* m1 = msg + ((size_t)(ent1 >> 1) * 8 + batA) * H + quad * 8;
      bf16x8 v0 = *(const bf16x8*)(m0);
      bf16x8 v1 = *(const bf16x8*)(m0 + 32);
      bf16x8 v2 = *(const bf16x8*)(m0 + 64);
      bf16x8 v3 = *(const bf16x8*)(m0 + 96);
      bf16x8 u0 = *(const bf16x8*)(m1);
      bf16x8 u1 = *(const bf16x8*)(m1 + 32);
      bf16x8 u2 = *(const bf16x8*)(m1 + 64);
      bf16x8 u3 = *(const bf16x8*)(m1 + 96);
      if (quad == 0) {
        float sg0 = (ent0 & 1) ? 1.0f : -1.0f;
        float sg1 = (ent1 & 1) ? 1.0f : -1.0f;
        const float* uv0 = updv + ((size_t)(ent0 >> 1) * 8 + batA) * 3;
        const float* uv1 = updv + ((size_t)(ent1 >> 1) * 8 + batA) * 3;
        sx += sg0 * uv0[0] + sg1 * uv1[0];
        sy += sg0 * uv0[1] + sg1 * uv1[1];
        sz += sg0 * uv0[2] + sg1 * uv1[2];
      }
#pragma unroll
      for (int t = 0; t < 8; t++) {
        a32[t]      += (float)v0[t] + (float)u0[t];
        a32[8 + t]  += (float)v1[t] + (float)u1[t];
        a32[16 + t] += (float)v2[t] + (float)u2[t];
        a32[24 + t] += (float)v3[t] + (float)u3[t];
      }
    }
    if (j < deg) {
      int ent0 = adj[off + j];
      const bf16* m0 = msg + ((size_t)(ent0 >> 1) * 8 + batA) * H + quad * 8;
      if (quad == 0) {
        float sg0 = (ent0 & 1) ? 1.0f : -1.0f;
        const float* uv0 = updv + ((size_t)(ent0 >> 1) * 8 + batA) * 3;
        sx += sg0 * uv0[0]; sy += sg0 * uv0[1]; sz += sg0 * uv0[2];
      }
#pragma unroll
      for (int k = 0; k < 4; k++) {
        bf16x8 v = *(const bf16x8*)(m0 + 32 * k);
#pragma unroll
        for (int t = 0; t < 8; t++) a32[8 * k + t] += (float)v[t];
      }
    }
  }

  // x finalize (one lane per row)
  if (quad == 0) {
    float cnt = deg < 1 ? 1.0f : (float)deg;
    float inv = 1.0f / cnt;
    size_t o = (size_t)Rg * 3;
    xout[o + 0] = x[o + 0] + sx * inv;
    xout[o + 1] = x[o + 1] + sy * inv;
    xout[o + 2] = x[o + 2] + sz * inv;
  }

  // MFMA the aggregated half
#pragma unroll
  for (int ks2 = 0; ks2 < 4; ks2++) {
    bf16x8 af;
#pragma unroll
    for (int t = 0; t < 8; t++) af[t] = (bf16)a32[8 * ks2 + t];
#pragma unroll
    for (int nt = 0; nt < 8; nt++) {
      bf16x8 b = W1v[(nt * 8 + 4 + ks2) * 64 + lane];
      acc[nt] = __builtin_amdgcn_mfma_f32_16x16x32_bf16(af, b, acc[nt], 0, 0, 0);
    }
  }
#pragma unroll
  for (int nt = 0; nt < 8; nt++) {
    int col = nt * 16 + l16;
    float bb = bn1[col];
#pragma unroll
    for (int reg = 0; reg < 4; reg++) {
      int row = rowBase + quad * 4 + reg;
      Tbuf[tswz(row, col)] = (bf16)silu_f(acc[nt][reg] + bb);
    }
  }

#pragma unroll
  for (int nt = 0; nt < 8; nt++) acc[nt] = (f32x4){0.f, 0.f, 0.f, 0.f};
#pragma unroll
  for (int ks = 0; ks < 4; ks++) {
    bf16x8 a = *(const bf16x8*)&Tbuf[tswz(rowBase + l16, ks * 32 + quad * 8)];
#pragma unroll
    for (int nt = 0; nt < 8; nt++) {
      bf16x8 b = W2v[(nt * 4 + ks) * 64 + lane];
      acc[nt] = __builtin_amdgcn_mfma_f32_16x16x32_bf16(a, b, acc[nt], 0, 0, 0);
    }
  }
#pragma unroll
  for (int nt = 0; nt < 8; nt++) {
    int col = nt * 16 + l16;
    float bb = bn2[col];
#pragma unroll
    for (int reg = 0; reg < 4; reg++) {
      size_t Ro = (size_t)blk * 64 + rowBase + quad * 4 + reg;
      hout[Ro * H + col] = h[Ro * H + col] + acc[nt][reg] + bb;
    }
  }
}

extern "C" void kernel_launch(void* const* d_in, const int* in_sizes, int n_in,
                              void* d_out, int out_size, void* d_ws,
                              size_t ws_size, hipStream_t stream) {
  const float* h    = (const float*)d_in[0];
  const float* x    = (const float*)d_in[1];
  const int*  bonds = (const int*)d_in[2];
  const float* Wm1  = (const float*)d_in[3];
  const float* bm1  = (const float*)d_in[4];
  const float* Wm2  = (const float*)d_in[5];
  const float* bm2  = (const float*)d_in[6];
  const float* Wn1  = (const float*)d_in[7];
  const float* bn1  = (const float*)d_in[8];
  const float* Wn2  = (const float*)d_in[9];
  const float* bn2  = (const float*)d_in[10];
  const float* Wc1  = (const float*)d_in[11];
  const float* bc1  = (const float*)d_in[12];
  const float* Wc2  = (const float*)d_in[13];

  float* out  = (float*)d_out;
  float* hout = out;
  float* xout = out + (size_t)NBATCH * NA * H;

  char* ws = (char*)d_ws;
  // layout (bytes): NEED = 170,655,744 < 173,080,576 proven available.
  const size_t OFF_DEG  = 0;                        // NA int
  const size_t OFF_OFFS = 81920;                    // NA int
  const size_t OFF_CUR  = 163840;                   // NA int
  const size_t OFF_ADJ  = 245760;                   // 2*NB int = 480,000 B
  const size_t OFF_W1   = 786432;                   // 65,536 B
  const size_t OFF_W2   = OFF_W1 + 65536;           // 32,768
  const size_t OFF_WN1  = OFF_W2 + 32768;           // 65,536
  const size_t OFF_WN2  = OFF_WN1 + 65536;          // 32,768
  const size_t OFF_WC1  = OFF_WN2 + 32768;          // 32,768 (ends 1,015,808)
  const size_t OFF_UPDV = 1048576;                  // NB*8*3 f32 = 5,760,000
  const size_t OFF_HB   = 6815744;                  // 160000*128 bf16 = 40,960,000
  const size_t OFF_MSG  = 47775744;                 // NB*8*128 bf16 = 122,880,000

  int*   degI = (int*)(ws + OFF_DEG);
  int*   offs = (int*)(ws + OFF_OFFS);
  int*   cur  = (int*)(ws + OFF_CUR);
  int*   adj  = (int*)(ws + OFF_ADJ);
  bf16*  W1p  = (bf16*)(ws + OFF_W1);
  bf16*  W2p  = (bf16*)(ws + OFF_W2);
  bf16*  Wn1p = (bf16*)(ws + OFF_WN1);
  bf16*  Wn2p = (bf16*)(ws + OFF_WN2);
  bf16*  Wc1p = (bf16*)(ws + OFF_WC1);
  float* updv = (float*)(ws + OFF_UPDV);
  bf16*  hb   = (bf16*)(ws + OFF_HB);
  bf16*  msgB = (bf16*)(ws + OFF_MSG);

  (void)hipMemsetAsync(degI, 0, NA * sizeof(int), stream);
  (void)hipMemsetAsync(cur, 0, NA * sizeof(int), stream);

  cast_h<<<NBATCH * NA * H / 1024, 256, 0, stream>>>(h, hb);
  pack_w<<<128, 256, 0, stream>>>(Wm1, W1p, 256);
  pack_w<<<64, 256, 0, stream>>>(Wm2, W2p, 128);
  pack_w<<<128, 256, 0, stream>>>(Wn1, Wn1p, 256);
  pack_w<<<64, 256, 0, stream>>>(Wn2, Wn2p, 128);
  pack_w<<<64, 256, 0, stream>>>(Wc1, Wc1p, 128);

  count_deg<<<(NB + 255) / 256, 256, 0, stream>>>(bonds, degI);
  scan_offsets<<<1, 1024, 0, stream>>>(degI, offs);
  build_adj<<<(NB + 255) / 256, 256, 0, stream>>>(bonds, offs, cur, adj);

  msg_kernel<<<NB * NBATCH / 64, 256, 0, stream>>>(
      hb, x, bonds, W1p, bm1, W2p, bm2, Wm1 + 256 * H, Wc1p, bc1, Wc2,
      msgB, updv);
  node_kernel<<<NBATCH * NA / 64, 256, 0, stream>>>(
      h, hb, msgB, updv, offs, degI, adj, Wn1p, bn1, Wn2p, bn2, x,
      hout, xout);
}